// Round 21
// baseline (440.979 us; speedup 1.0000x reference)
//
#include <hip/hip_runtime.h>

#define NN 65536
#define NE 1048576
#define NODE_F 32
#define EDGE_F 8
#define HID 64
#define NBATCH 64
#define NB 256
#define EPB (NE / NB)     // 4096 edges per P1/P3 block -> 4 edges/(blk,bin)
#define NBIN 1024         // bin = tgt >> 6
#define CAP 2048          // max edges per bin (mean 1024)
#define NREP 64           // output replicas for batch-sum atomics

typedef __attribute__((ext_vector_type(8))) short s16x8;
typedef __attribute__((ext_vector_type(4))) float f32x4;

union FragU { s16x8 s; uint u[4]; };

// pack two f32 -> two bf16 (RNE) in one u32  [verified R1-R19; do NOT replace
// with inline-asm v_cvt_pk_bf16_f32 — R20 produced NaN]
__device__ inline uint pk2(float a, float b) {
    uint ua = __float_as_uint(a); ua += 0x7FFFu + ((ua >> 16) & 1u);
    uint ub = __float_as_uint(b); ub += 0x7FFFu + ((ub >> 16) & 1u);
    return (ua >> 16) | (ub & 0xFFFF0000u);
}

// ---------------- support = act(x) @ W  (x:[N,K], W:[K,64]) ----------------
template<int K, bool RELUB>
__global__ __launch_bounds__(256) void node_linear(const float* __restrict__ x,
                                                   const float* __restrict__ pb,
                                                   const float* __restrict__ W,
                                                   float* __restrict__ out, int n_nodes) {
    const int lane = threadIdx.x & 63;
    const int wv = threadIdx.x >> 6;
    float wr[K];
#pragma unroll
    for (int k = 0; k < K; ++k) wr[k] = W[k * HID + lane];
    int wid = blockIdx.x * 4 + wv;
    const int nw = gridDim.x * 4;
    for (int n0 = wid; n0 < n_nodes; n0 += nw) {
        const int n = __builtin_amdgcn_readfirstlane(n0);
        const float* xr = x + (size_t)n * K;
        float acc = 0.f;
#pragma unroll
        for (int k = 0; k < K; ++k) {
            float xk = xr[k];
            if (RELUB) xk = fmaxf(xk + pb[k], 0.f);
            acc = fmaf(xk, wr[k], acc);
        }
        out[(size_t)n * HID + lane] = acc;
    }
}

// ---------------- sort pass 1: per-block bin histogram (+ global bin totals) --
__global__ __launch_bounds__(1024) void p1_hist(const int* __restrict__ Etgt, int* __restrict__ bc,
                                                int* __restrict__ binTotal) {
    __shared__ int h[NBIN];
    const int blk = blockIdx.x;
    if (threadIdx.x < NBIN) h[threadIdx.x] = 0;
    __syncthreads();
    const int base = blk * EPB;
#pragma unroll
    for (int c = 0; c < EPB / 1024; ++c)
        atomicAdd(&h[((uint)Etgt[base + c * 1024 + threadIdx.x]) >> 6], 1);
    __syncthreads();
    if (threadIdx.x < NBIN) {
        const int v = h[threadIdx.x];
        bc[blk * NBIN + threadIdx.x] = v;
        if (v) atomicAdd(&binTotal[threadIdx.x], v);
    }
}

// ---------------- sort pass 2: binStart (wave-reduce) + per-bin block prefix --
__global__ __launch_bounds__(256) void p2_cursor(const int* __restrict__ binTotal,
                                                 const int* __restrict__ bc,
                                                 int* __restrict__ binStart,
                                                 int* __restrict__ cursor) {
    const int lane = threadIdx.x & 63;
    const int wv = threadIdx.x >> 6;
    const int bin = blockIdx.x * 4 + wv;
    int s = 0;
#pragma unroll
    for (int c = 0; c < NBIN / 64; ++c) {
        const int t = c * 64 + lane;
        if (t < bin) s += binTotal[t];
    }
#pragma unroll
    for (int off = 32; off >= 1; off >>= 1) s += __shfl_xor(s, off, 64);
    int carry = s;
    if (lane == 0) {
        binStart[bin] = carry;
        if (bin == NBIN - 1) binStart[NBIN] = carry + binTotal[bin];
    }
    for (int c = 0; c < NB; c += 64) {
        const int blk = c + lane;
        const int v = bc[blk * NBIN + bin];
        int incl = v;
#pragma unroll
        for (int d = 1; d < 64; d <<= 1) {
            const int u = __shfl_up(incl, d, 64);
            if (lane >= d) incl += u;
        }
        cursor[blk * NBIN + bin] = carry + incl - v;
        carry += __shfl(incl, 63, 64);
    }
}

// ---------------- sort pass 3: scatter into bin regions + layer-3 enc ---------
__global__ __launch_bounds__(1024) void p3_scatter(
    const int* __restrict__ Etgt, const int* __restrict__ Esrc, const float* __restrict__ ef,
    const int* __restrict__ cursor,
    const float* __restrict__ oW1, const float* __restrict__ ob1,
    const float* __restrict__ oW2, const float* __restrict__ ob2,
    uint4* __restrict__ ef16_t, uint2* __restrict__ meta_t)
{
    __shared__ int cur[NBIN];
    const int blk = blockIdx.x;
    if (threadIdx.x < NBIN) cur[threadIdx.x] = cursor[blk * NBIN + threadIdx.x];
    float w[8];
#pragma unroll
    for (int k = 0; k < 8; ++k) w[k] = oW1[k];
    const float b1v = ob1[0], w2 = oW2[0], b2v = ob2[0];
    __syncthreads();
    const int base = blk * EPB;
#pragma unroll
    for (int c = 0; c < EPB / 1024; ++c) {
        const int i = base + c * 1024 + threadIdx.x;
        const int tgt = Etgt[i];
        const int p = atomicAdd(&cur[(uint)tgt >> 6], 1);
        const float4 x = *(const float4*)(ef + (size_t)i * 8);
        const float4 y = *(const float4*)(ef + (size_t)i * 8 + 4);
        uint4 u;
        u.x = pk2(x.x, x.y); u.y = pk2(x.z, x.w);
        u.z = pk2(y.x, y.y); u.w = pk2(y.z, y.w);
        ef16_t[p] = u;
        float h = b1v;
        h = fmaf(x.x, w[0], h); h = fmaf(x.y, w[1], h);
        h = fmaf(x.z, w[2], h); h = fmaf(x.w, w[3], h);
        h = fmaf(y.x, w[4], h); h = fmaf(y.y, w[5], h);
        h = fmaf(y.z, w[6], h); h = fmaf(y.w, w[7], h);
        uint2 m;
        m.x = (uint)Esrc[i] | ((uint)tgt << 16);
        m.y = __float_as_uint(fmaxf(h, 0.f) * w2 + b2v);
        meta_t[p] = m;
    }
}

// ---------------- sort pass 4: per-bin LDS counting sort by tgt&63 ----------
__global__ __launch_bounds__(256) void p4_sort(
    const int* __restrict__ binStart, const uint2* __restrict__ meta_t,
    const uint4* __restrict__ ef16_t,
    uint2* __restrict__ meta, uint4* __restrict__ ef16)
{
    __shared__ uint s_stp[CAP];
    __shared__ int rk[CAP];
    __shared__ int cnt[64], off[64];
    const int b = blockIdx.x;
    const int beg = binStart[b], end = binStart[b + 1];
    const int n = end - beg;
    if (threadIdx.x < 64) cnt[threadIdx.x] = 0;
    __syncthreads();
    for (int j = threadIdx.x; j < n; j += 256) {
        const uint v = meta_t[beg + j].x;
        s_stp[j] = v;
        rk[j] = atomicAdd(&cnt[(v >> 16) & 63], 1);
    }
    __syncthreads();
    if (threadIdx.x == 0) {
        int run = 0;
#pragma unroll
        for (int k = 0; k < 64; ++k) { off[k] = run; run += cnt[k]; }
    }
    __syncthreads();
    for (int j = threadIdx.x; j < n; j += 256) {
        const uint v = s_stp[j];
        const int pos = beg + off[(v >> 16) & 63] + rk[j];
        meta[pos] = meta_t[beg + j];
        ef16[pos] = ef16_t[beg + j];
    }
}

// ---------------- fused: MFMA edge-MLP (enc in LDS) + pipelined segmented agg --
#define ISSUE(BUF, BASE_)                                                        \
    _Pragma("unroll")                                                            \
    for (int jj = 0; jj < 16; ++jj) {                                            \
        const uint stj = (uint)__builtin_amdgcn_readlane((int)st_l, (BASE_) + jj); \
        sv##BUF[jj] = support[(size_t)(stj & 0xFFFFu) * HID + lane];             \
    }

#define PROC(BUF, BASE_)                                                         \
    _Pragma("unroll")                                                            \
    for (int jj = 0; jj < 16; ++jj) {                                            \
        const int j = (BASE_) + jj;                                              \
        const int tgt = (int)((uint)__builtin_amdgcn_readlane((int)st_l, j) >> 16); \
        const ushort eu = *(const ushort*)(lds + j * 128 + ((lane * 2) ^ ((j & 7) << 4))); \
        const float ev = __uint_as_float((uint)eu << 16);                        \
        if (tgt != tprev) {                                                      \
            float* dst = agg + (size_t)tprev * HID + lane;                       \
            if (first) { atomicAdd(dst, acc); first = 0; }                       \
            else *dst = acc;                                                     \
            acc = 0.f; tprev = tgt;                                              \
        }                                                                        \
        acc = fmaf(sv##BUF[jj], ev, acc);                                        \
    }

__global__ __launch_bounds__(256, 4) void edge_layer_fused(
    const uint4* __restrict__ ef16, const uint2* __restrict__ meta,
    const float* __restrict__ support,
    const float* __restrict__ W1, const float* __restrict__ b1,
    const float* __restrict__ W2, const float* __restrict__ b2,
    float* __restrict__ agg)
{
    __shared__ ushort lds_all[4][32 * 64];   // 4 KB per wave
    const int lane = threadIdx.x & 63;
    const int wv = threadIdx.x >> 6;
    char* lds = (char*)lds_all[wv];
    const int l15 = lane & 15, lhi = lane >> 4;
    const int swz = (l15 & 7) << 4;

    FragU a1[4];
#pragma unroll
    for (int mt = 0; mt < 4; ++mt) {
        a1[mt].u[0] = a1[mt].u[1] = a1[mt].u[2] = a1[mt].u[3] = 0;
        const int h = l15 + 16 * mt;
        if (lhi == 0) {
#pragma unroll
            for (int j = 0; j < 4; ++j)
                a1[mt].u[j] = pk2(W1[(2 * j) * HID + h], W1[(2 * j + 1) * HID + h]);
        } else if (lhi == 1) {
            a1[mt].u[0] = pk2(b1[h], 0.f);
        }
    }
    FragU a2[4][2];
#pragma unroll
    for (int mt = 0; mt < 4; ++mt)
#pragma unroll
        for (int kc = 0; kc < 2; ++kc) {
            const int o = l15 + 16 * mt;
            const int k0 = 32 * kc + 8 * lhi;
#pragma unroll
            for (int j = 0; j < 4; ++j)
                a2[mt][kc].u[j] = pk2(W2[(k0 + 2 * j) * HID + o], W2[(k0 + 2 * j + 1) * HID + o]);
        }
    // b2 folded into GEMM2's C operand (output row = 16*mt + 4*lhi + r)
    float b2v[4][4];
#pragma unroll
    for (int mt = 0; mt < 4; ++mt)
#pragma unroll
        for (int r = 0; r < 4; ++r)
            b2v[mt][r] = b2[16 * mt + 4 * lhi + r];

    for (int tile = blockIdx.x * 4 + wv; tile < NE / 32; tile += gridDim.x * 4) {
        const size_t ebase = (size_t)tile * 32;
        const uint st_l = meta[ebase + (lane & 31)].x;   // src|tgt<<16

        // ---- GEMM1: H^T = W1^T @ [EF^T; 1] -> LDS (relu'd, bf16, swizzled) ----
#pragma unroll
        for (int nt = 0; nt < 2; ++nt) {
            FragU bf;
            bf.u[0] = bf.u[1] = bf.u[2] = bf.u[3] = 0;
            if (lhi == 0) {
                const uint4 u = ef16[ebase + nt * 16 + l15];
                bf.u[0] = u.x; bf.u[1] = u.y; bf.u[2] = u.z; bf.u[3] = u.w;
            } else if (lhi == 1) {
                bf.u[0] = 0x3F80u;   // B[k=8][e] = 1.0 (bias row)
            }
            const int ebyte = (l15 + 16 * nt) * 128;
#pragma unroll
            for (int mt = 0; mt < 4; ++mt) {
                f32x4 c = {0.f, 0.f, 0.f, 0.f};
                c = __builtin_amdgcn_mfma_f32_16x16x32_bf16(a1[mt].s, bf.s, c, 0, 0, 0);
                uint2 w;
                w.x = pk2(fmaxf(c[0], 0.f), fmaxf(c[1], 0.f));
                w.y = pk2(fmaxf(c[2], 0.f), fmaxf(c[3], 0.f));
                const int hb = (16 * mt + 4 * lhi) * 2;
                *(uint2*)(lds + ebyte + (hb ^ swz)) = w;
            }
        }

        // ---- prefetch all 32 support gathers; GEMM2 (no vmem) hides latency ----
        float svA[16], svB[16];
        int tprev = (int)((uint)__builtin_amdgcn_readlane((int)st_l, 0) >> 16);
        int first = 1;
        float acc = 0.f;
        ISSUE(A, 0)
        ISSUE(B, 16)

        // ---- GEMM2: ENC^T = W2^T @ H^T + b2 (C operand) ----
#pragma unroll
        for (int nt = 0; nt < 2; ++nt) {
            const int ebyte = (l15 + 16 * nt) * 128;
            const s16x8 bh0 = *(const s16x8*)(lds + ebyte + ((16 * lhi + 0) ^ swz));
            const s16x8 bh1 = *(const s16x8*)(lds + ebyte + ((16 * lhi + 64) ^ swz));
#pragma unroll
            for (int mt = 0; mt < 4; ++mt) {
                f32x4 c = {b2v[mt][0], b2v[mt][1], b2v[mt][2], b2v[mt][3]};
                c = __builtin_amdgcn_mfma_f32_16x16x32_bf16(a2[mt][0].s, bh0, c, 0, 0, 0);
                c = __builtin_amdgcn_mfma_f32_16x16x32_bf16(a2[mt][1].s, bh1, c, 0, 0, 0);
                uint2 w;
                w.x = pk2(c[0], c[1]);
                w.y = pk2(c[2], c[3]);
                const int ob = (16 * mt + 4 * lhi) * 2;
                *(uint2*)(lds + ebyte + (ob ^ swz)) = w;
            }
        }

        // ---- phase 2: segmented aggregation over the 32 sorted edges ----
        PROC(A, 0)
        PROC(B, 16)
        atomicAdd(agg + (size_t)tprev * HID + lane, acc);
    }
}

// ---------------- sup3[n] = relu(x[n,:]+pb) . w ----------------
__global__ __launch_bounds__(256) void node_dot(const float* __restrict__ x, const float* __restrict__ pb,
                                                const float* __restrict__ w,
                                                float* __restrict__ out, int n_nodes) {
    const int lane = threadIdx.x & 63;
    const int wv = threadIdx.x >> 6;
    const float wk = w[lane];
    const float pbv = pb[lane];
    int wid = blockIdx.x * 4 + wv;
    const int nw = gridDim.x * 4;
    for (int n = wid; n < n_nodes; n += nw) {
        float v = fmaxf(x[(size_t)n * HID + lane] + pbv, 0.f) * wk;
#pragma unroll
        for (int off = 32; off >= 1; off >>= 1) v += __shfl_xor(v, off, 64);
        if (lane == 0) out[n] = v;
    }
}

// ---------------- layer-3: segmented batch-sum -> 64-replica scratch ---------
__global__ __launch_bounds__(256) void edge_out_seg(
    const uint2* __restrict__ meta,
    const float* __restrict__ sup3, const int* __restrict__ batch,
    float* __restrict__ outR)
{
    const int lane = threadIdx.x & 63;
    const int wv = threadIdx.x >> 6;
    const int wid = blockIdx.x * 4 + wv;
    float* outw = outR + (size_t)(wid & (NREP - 1)) * NBATCH;
    const size_t base = (size_t)wid * 128;
    float acc = 0.f;
    int bcur = -1;
#pragma unroll
    for (int c = 0; c < 2; ++c) {
        const size_t i = base + c * 64 + lane;
        const uint2 m = meta[i];
        const float mv = sup3[m.x & 0xFFFFu] * __uint_as_float(m.y);
        const int b = batch[m.x >> 16];
        if (b != bcur) {
            if (bcur >= 0) atomicAdd(&outw[bcur], acc);
            bcur = b;
            acc = mv;
        } else {
            acc += mv;
        }
    }
    const int b0 = __builtin_amdgcn_readfirstlane(bcur);
    if (__all(bcur == b0)) {
#pragma unroll
        for (int off = 32; off >= 1; off >>= 1) acc += __shfl_xor(acc, off, 64);
        if (lane == 0) atomicAdd(&outw[b0], acc);
    } else {
        atomicAdd(&outw[bcur], acc);
    }
}

// ---------------- pool bias + replica reduction (block 0) --------------------
__global__ __launch_bounds__(256) void pool_bias_final(const int* __restrict__ batch,
                                                       const float* __restrict__ b_out,
                                                       const float* __restrict__ outR,
                                                       float* __restrict__ out) {
    __shared__ int cnt[NBATCH];
    if (threadIdx.x < NBATCH) cnt[threadIdx.x] = 0;
    __syncthreads();
    const int n = blockIdx.x * 256 + threadIdx.x;
    atomicAdd(&cnt[batch[n]], 1);
    __syncthreads();
    if (threadIdx.x < NBATCH && cnt[threadIdx.x])
        atomicAdd(&out[threadIdx.x], (float)cnt[threadIdx.x] * b_out[0]);
    if (blockIdx.x == 0 && threadIdx.x < NBATCH) {
        float s = 0.f;
#pragma unroll
        for (int r = 0; r < NREP; ++r) s += outR[r * NBATCH + threadIdx.x];
        atomicAdd(&out[threadIdx.x], s);
    }
}

extern "C" void kernel_launch(void* const* d_in, const int* in_sizes, int n_in,
                              void* d_out, int out_size, void* d_ws, size_t ws_size,
                              hipStream_t stream) {
    const float* nf    = (const float*)d_in[0];
    const float* ef    = (const float*)d_in[1];
    const int*   Esrc  = (const int*)d_in[2];
    const int*   Etgt  = (const int*)d_in[3];
    const int*   batch = (const int*)d_in[4];
    const float* W_in  = (const float*)d_in[5];
    const float* b_in  = (const float*)d_in[6];
    const float* W_mid = (const float*)d_in[7];
    const float* b_mid = (const float*)d_in[8];
    const float* W_out = (const float*)d_in[9];
    const float* b_out = (const float*)d_in[10];
    const float* eiW1  = (const float*)d_in[11];
    const float* eib1  = (const float*)d_in[12];
    const float* eiW2  = (const float*)d_in[13];
    const float* eib2  = (const float*)d_in[14];
    const float* emW1  = (const float*)d_in[15];
    const float* emb1  = (const float*)d_in[16];
    const float* emW2  = (const float*)d_in[17];
    const float* emb2  = (const float*)d_in[18];
    const float* eoW1  = (const float*)d_in[19];
    const float* eob1  = (const float*)d_in[20];
    const float* eoW2  = (const float*)d_in[21];
    const float* eob2  = (const float*)d_in[22];

    float* bufA   = (float*)d_ws;                        // 16MB support
    float* bufB   = bufA + (size_t)NN * HID;             // 16MB x/agg
    float* sup3   = bufB + (size_t)NN * HID;             // 256KB
    uint4* ef16   = (uint4*)(sup3 + NN);                 // 16MB sorted packed ef
    uint2* meta   = (uint2*)(ef16 + NE);                 // 8MB {src|tgt, enc3}
    uint4* ef16_t = (uint4*)(meta + NE);                 // 16MB bin-staged ef
    uint2* meta_t = (uint2*)(ef16_t + NE);               // 8MB bin-staged meta
    int* bc       = (int*)(meta_t + NE);                 // 1MB per-block bin counts
    int* cursor   = bc + NB * NBIN;                      // 1MB per-(blk,bin) cursors
    int* binStart = cursor + NB * NBIN;                  // 4KB+
    int* binTotal = binStart + NBIN + 1;                 // 4KB
    float* outR   = (float*)(binTotal + NBIN);           // 16KB replicas

    hipMemsetAsync(d_out, 0, NBATCH * sizeof(float), stream);
    // binTotal and outR are contiguous: clear both in one memset
    hipMemsetAsync(binTotal, 0, (NBIN + NREP * NBATCH) * sizeof(int), stream);

    // 2-level LDS-binned sort by Etgt (+ layer-3 enc computed in-flight)
    p1_hist<<<NB, 1024, 0, stream>>>(Etgt, bc, binTotal);
    p2_cursor<<<NBIN / 4, 256, 0, stream>>>(binTotal, bc, binStart, cursor);
    p3_scatter<<<NB, 1024, 0, stream>>>(Etgt, Esrc, ef, cursor,
                                        eoW1, eob1, eoW2, eob2, ef16_t, meta_t);
    p4_sort<<<NBIN, 256, 0, stream>>>(binStart, meta_t, ef16_t, meta, ef16);

    // layer 1
    node_linear<NODE_F, false><<<1024, 256, 0, stream>>>(nf, nullptr, W_in, bufA, NN);
    hipMemsetAsync(bufB, 0, (size_t)NN * HID * sizeof(float), stream);
    edge_layer_fused<<<2048, 256, 0, stream>>>(ef16, meta, bufA, eiW1, eib1, eiW2, eib2, bufB);
    // layer 2
    node_linear<HID, true><<<1024, 256, 0, stream>>>(bufB, b_in, W_mid, bufA, NN);
    hipMemsetAsync(bufB, 0, (size_t)NN * HID * sizeof(float), stream);
    edge_layer_fused<<<2048, 256, 0, stream>>>(ef16, meta, bufA, emW1, emb1, emW2, emb2, bufB);
    // layer 3 + pooling (exact f32, segmented batch accumulation -> replicas)
    node_dot<<<256, 256, 0, stream>>>(bufB, b_mid, W_out, sup3, NN);
    edge_out_seg<<<NE / 512, 256, 0, stream>>>(meta, sup3, batch, outR);
    pool_bias_final<<<NN / 256, 256, 0, stream>>>(batch, b_out, outR, (float*)d_out);
}

// Round 22
// 286.046 us; speedup vs baseline: 1.5416x; 1.5416x over previous
//
#include <hip/hip_runtime.h>

#define NN 65536
#define NE 1048576
#define NODE_F 32
#define EDGE_F 8
#define HID 64
#define NBATCH 64
#define NB 256
#define EPB (NE / NB)     // 4096 edges per P1/P3 block -> 4 edges/(blk,bin)
#define NBIN 1024         // bin = tgt >> 6
#define CAP 2048          // max edges per bin (mean 1024)
#define NREP 64           // output replicas for batch-sum atomics

typedef __attribute__((ext_vector_type(8))) short s16x8;
typedef __attribute__((ext_vector_type(4))) float f32x4;

union FragU { s16x8 s; uint u[4]; };

// pack two f32 -> two bf16 (RNE) in one u32  [verified R1-R19; inline-asm
// v_cvt_pk_bf16_f32 (R20) => NaN; b2-fold into MFMA C (R21) => spill cliff]
__device__ inline uint pk2(float a, float b) {
    uint ua = __float_as_uint(a); ua += 0x7FFFu + ((ua >> 16) & 1u);
    uint ub = __float_as_uint(b); ub += 0x7FFFu + ((ub >> 16) & 1u);
    return (ua >> 16) | (ub & 0xFFFF0000u);
}

// ---------------- support = act(x) @ W  (x:[N,K], W:[K,64]) ----------------
template<int K, bool RELUB>
__global__ __launch_bounds__(256) void node_linear(const float* __restrict__ x,
                                                   const float* __restrict__ pb,
                                                   const float* __restrict__ W,
                                                   float* __restrict__ out, int n_nodes) {
    const int lane = threadIdx.x & 63;
    const int wv = threadIdx.x >> 6;
    float wr[K];
#pragma unroll
    for (int k = 0; k < K; ++k) wr[k] = W[k * HID + lane];
    int wid = blockIdx.x * 4 + wv;
    const int nw = gridDim.x * 4;
    for (int n0 = wid; n0 < n_nodes; n0 += nw) {
        const int n = __builtin_amdgcn_readfirstlane(n0);
        const float* xr = x + (size_t)n * K;
        float acc = 0.f;
#pragma unroll
        for (int k = 0; k < K; ++k) {
            float xk = xr[k];
            if (RELUB) xk = fmaxf(xk + pb[k], 0.f);
            acc = fmaf(xk, wr[k], acc);
        }
        out[(size_t)n * HID + lane] = acc;
    }
}

// ---------------- sort pass 1: per-block bin histogram (+ global bin totals) --
__global__ __launch_bounds__(1024) void p1_hist(const int* __restrict__ Etgt, int* __restrict__ bc,
                                                int* __restrict__ binTotal) {
    __shared__ int h[NBIN];
    const int blk = blockIdx.x;
    if (threadIdx.x < NBIN) h[threadIdx.x] = 0;
    __syncthreads();
    const int base = blk * EPB;
#pragma unroll
    for (int c = 0; c < EPB / 1024; ++c)
        atomicAdd(&h[((uint)Etgt[base + c * 1024 + threadIdx.x]) >> 6], 1);
    __syncthreads();
    if (threadIdx.x < NBIN) {
        const int v = h[threadIdx.x];
        bc[blk * NBIN + threadIdx.x] = v;
        if (v) atomicAdd(&binTotal[threadIdx.x], v);
    }
}

// ---------------- sort pass 2: binStart (wave-reduce) + per-bin block prefix --
__global__ __launch_bounds__(256) void p2_cursor(const int* __restrict__ binTotal,
                                                 const int* __restrict__ bc,
                                                 int* __restrict__ binStart,
                                                 int* __restrict__ cursor) {
    const int lane = threadIdx.x & 63;
    const int wv = threadIdx.x >> 6;
    const int bin = blockIdx.x * 4 + wv;
    int s = 0;
#pragma unroll
    for (int c = 0; c < NBIN / 64; ++c) {
        const int t = c * 64 + lane;
        if (t < bin) s += binTotal[t];
    }
#pragma unroll
    for (int off = 32; off >= 1; off >>= 1) s += __shfl_xor(s, off, 64);
    int carry = s;
    if (lane == 0) {
        binStart[bin] = carry;
        if (bin == NBIN - 1) binStart[NBIN] = carry + binTotal[bin];
    }
    for (int c = 0; c < NB; c += 64) {
        const int blk = c + lane;
        const int v = bc[blk * NBIN + bin];
        int incl = v;
#pragma unroll
        for (int d = 1; d < 64; d <<= 1) {
            const int u = __shfl_up(incl, d, 64);
            if (lane >= d) incl += u;
        }
        cursor[blk * NBIN + bin] = carry + incl - v;
        carry += __shfl(incl, 63, 64);
    }
}

// ---------------- sort pass 3: scatter into bin regions + layer-3 enc ---------
__global__ __launch_bounds__(1024) void p3_scatter(
    const int* __restrict__ Etgt, const int* __restrict__ Esrc, const float* __restrict__ ef,
    const int* __restrict__ cursor,
    const float* __restrict__ oW1, const float* __restrict__ ob1,
    const float* __restrict__ oW2, const float* __restrict__ ob2,
    uint4* __restrict__ ef16_t, uint2* __restrict__ meta_t)
{
    __shared__ int cur[NBIN];
    const int blk = blockIdx.x;
    if (threadIdx.x < NBIN) cur[threadIdx.x] = cursor[blk * NBIN + threadIdx.x];
    float w[8];
#pragma unroll
    for (int k = 0; k < 8; ++k) w[k] = oW1[k];
    const float b1v = ob1[0], w2 = oW2[0], b2v = ob2[0];
    __syncthreads();
    const int base = blk * EPB;
#pragma unroll
    for (int c = 0; c < EPB / 1024; ++c) {
        const int i = base + c * 1024 + threadIdx.x;
        const int tgt = Etgt[i];
        const int p = atomicAdd(&cur[(uint)tgt >> 6], 1);
        const float4 x = *(const float4*)(ef + (size_t)i * 8);
        const float4 y = *(const float4*)(ef + (size_t)i * 8 + 4);
        uint4 u;
        u.x = pk2(x.x, x.y); u.y = pk2(x.z, x.w);
        u.z = pk2(y.x, y.y); u.w = pk2(y.z, y.w);
        ef16_t[p] = u;
        float h = b1v;
        h = fmaf(x.x, w[0], h); h = fmaf(x.y, w[1], h);
        h = fmaf(x.z, w[2], h); h = fmaf(x.w, w[3], h);
        h = fmaf(y.x, w[4], h); h = fmaf(y.y, w[5], h);
        h = fmaf(y.z, w[6], h); h = fmaf(y.w, w[7], h);
        uint2 m;
        m.x = (uint)Esrc[i] | ((uint)tgt << 16);
        m.y = __float_as_uint(fmaxf(h, 0.f) * w2 + b2v);
        meta_t[p] = m;
    }
}

// ---------------- sort pass 4: per-bin LDS counting sort by tgt&63 ----------
__global__ __launch_bounds__(256) void p4_sort(
    const int* __restrict__ binStart, const uint2* __restrict__ meta_t,
    const uint4* __restrict__ ef16_t,
    uint2* __restrict__ meta, uint4* __restrict__ ef16)
{
    __shared__ uint s_stp[CAP];
    __shared__ int rk[CAP];
    __shared__ int cnt[64], off[64];
    const int b = blockIdx.x;
    const int beg = binStart[b], end = binStart[b + 1];
    const int n = end - beg;
    if (threadIdx.x < 64) cnt[threadIdx.x] = 0;
    __syncthreads();
    for (int j = threadIdx.x; j < n; j += 256) {
        const uint v = meta_t[beg + j].x;
        s_stp[j] = v;
        rk[j] = atomicAdd(&cnt[(v >> 16) & 63], 1);
    }
    __syncthreads();
    if (threadIdx.x == 0) {
        int run = 0;
#pragma unroll
        for (int k = 0; k < 64; ++k) { off[k] = run; run += cnt[k]; }
    }
    __syncthreads();
    for (int j = threadIdx.x; j < n; j += 256) {
        const uint v = s_stp[j];
        const int pos = beg + off[(v >> 16) & 63] + rk[j];
        meta[pos] = meta_t[beg + j];
        ef16[pos] = ef16_t[beg + j];
    }
}

// ---------------- fused: MFMA edge-MLP (enc in LDS) + pipelined segmented agg --
#define ISSUE(BUF, BASE_)                                                        \
    _Pragma("unroll")                                                            \
    for (int jj = 0; jj < 16; ++jj) {                                            \
        const uint stj = (uint)__builtin_amdgcn_readlane((int)st_l, (BASE_) + jj); \
        sv##BUF[jj] = support[(size_t)(stj & 0xFFFFu) * HID + lane];             \
    }

#define PROC(BUF, BASE_)                                                         \
    _Pragma("unroll")                                                            \
    for (int jj = 0; jj < 16; ++jj) {                                            \
        const int j = (BASE_) + jj;                                              \
        const int tgt = (int)((uint)__builtin_amdgcn_readlane((int)st_l, j) >> 16); \
        const ushort eu = *(const ushort*)(lds + j * 128 + ((lane * 2) ^ ((j & 7) << 4))); \
        const float ev = __uint_as_float((uint)eu << 16) + b2l;                  \
        if (tgt != tprev) {                                                      \
            float* dst = agg + (size_t)tprev * HID + lane;                       \
            if (first) { atomicAdd(dst, acc); first = 0; }                       \
            else *dst = acc;                                                     \
            acc = 0.f; tprev = tgt;                                              \
        }                                                                        \
        acc = fmaf(sv##BUF[jj], ev, acc);                                        \
    }

__global__ __launch_bounds__(256, 4) void edge_layer_fused(
    const uint4* __restrict__ ef16, const uint2* __restrict__ meta,
    const float* __restrict__ support,
    const float* __restrict__ W1, const float* __restrict__ b1,
    const float* __restrict__ W2, const float* __restrict__ b2,
    float* __restrict__ agg)
{
    __shared__ ushort lds_all[4][32 * 64];   // 4 KB per wave
    const int lane = threadIdx.x & 63;
    const int wv = threadIdx.x >> 6;
    char* lds = (char*)lds_all[wv];
    const int l15 = lane & 15, lhi = lane >> 4;
    const int swz = (l15 & 7) << 4;
    const float b2l = b2[lane];

    FragU a1[4];
#pragma unroll
    for (int mt = 0; mt < 4; ++mt) {
        a1[mt].u[0] = a1[mt].u[1] = a1[mt].u[2] = a1[mt].u[3] = 0;
        const int h = l15 + 16 * mt;
        if (lhi == 0) {
#pragma unroll
            for (int j = 0; j < 4; ++j)
                a1[mt].u[j] = pk2(W1[(2 * j) * HID + h], W1[(2 * j + 1) * HID + h]);
        } else if (lhi == 1) {
            a1[mt].u[0] = pk2(b1[h], 0.f);
        }
    }
    FragU a2[4][2];
#pragma unroll
    for (int mt = 0; mt < 4; ++mt)
#pragma unroll
        for (int kc = 0; kc < 2; ++kc) {
            const int o = l15 + 16 * mt;
            const int k0 = 32 * kc + 8 * lhi;
#pragma unroll
            for (int j = 0; j < 4; ++j)
                a2[mt][kc].u[j] = pk2(W2[(k0 + 2 * j) * HID + o], W2[(k0 + 2 * j + 1) * HID + o]);
        }

    for (int tile = blockIdx.x * 4 + wv; tile < NE / 32; tile += gridDim.x * 4) {
        const size_t ebase = (size_t)tile * 32;
        const uint st_l = meta[ebase + (lane & 31)].x;   // src|tgt<<16

        // ---- GEMM1: H^T = W1^T @ [EF^T; 1] -> LDS (relu'd, bf16, swizzled) ----
#pragma unroll
        for (int nt = 0; nt < 2; ++nt) {
            FragU bf;
            bf.u[0] = bf.u[1] = bf.u[2] = bf.u[3] = 0;
            if (lhi == 0) {
                const uint4 u = ef16[ebase + nt * 16 + l15];
                bf.u[0] = u.x; bf.u[1] = u.y; bf.u[2] = u.z; bf.u[3] = u.w;
            } else if (lhi == 1) {
                bf.u[0] = 0x3F80u;   // B[k=8][e] = 1.0 (bias row)
            }
            const int ebyte = (l15 + 16 * nt) * 128;
#pragma unroll
            for (int mt = 0; mt < 4; ++mt) {
                f32x4 c = {0.f, 0.f, 0.f, 0.f};
                c = __builtin_amdgcn_mfma_f32_16x16x32_bf16(a1[mt].s, bf.s, c, 0, 0, 0);
                uint2 w;
                w.x = pk2(fmaxf(c[0], 0.f), fmaxf(c[1], 0.f));
                w.y = pk2(fmaxf(c[2], 0.f), fmaxf(c[3], 0.f));
                const int hb = (16 * mt + 4 * lhi) * 2;
                *(uint2*)(lds + ebyte + (hb ^ swz)) = w;
            }
        }

        // ---- prefetch all 32 support gathers; GEMM2 (no vmem) hides latency ----
        float svA[16], svB[16];
        int tprev = (int)((uint)__builtin_amdgcn_readlane((int)st_l, 0) >> 16);
        int first = 1;
        float acc = 0.f;
        ISSUE(A, 0)
        ISSUE(B, 16)

        // ---- GEMM2: ENC^T = W2^T @ H^T (raw, b2 added in phase 2) ----
#pragma unroll
        for (int nt = 0; nt < 2; ++nt) {
            const int ebyte = (l15 + 16 * nt) * 128;
            const s16x8 bh0 = *(const s16x8*)(lds + ebyte + ((16 * lhi + 0) ^ swz));
            const s16x8 bh1 = *(const s16x8*)(lds + ebyte + ((16 * lhi + 64) ^ swz));
#pragma unroll
            for (int mt = 0; mt < 4; ++mt) {
                f32x4 c = {0.f, 0.f, 0.f, 0.f};
                c = __builtin_amdgcn_mfma_f32_16x16x32_bf16(a2[mt][0].s, bh0, c, 0, 0, 0);
                c = __builtin_amdgcn_mfma_f32_16x16x32_bf16(a2[mt][1].s, bh1, c, 0, 0, 0);
                uint2 w;
                w.x = pk2(c[0], c[1]);
                w.y = pk2(c[2], c[3]);
                const int ob = (16 * mt + 4 * lhi) * 2;
                *(uint2*)(lds + ebyte + (ob ^ swz)) = w;
            }
        }

        // ---- phase 2: segmented aggregation over the 32 sorted edges ----
        PROC(A, 0)
        PROC(B, 16)
        atomicAdd(agg + (size_t)tprev * HID + lane, acc);
    }
}

// ---------------- sup3[n] = relu(x[n,:]+pb) . w ----------------
__global__ __launch_bounds__(256) void node_dot(const float* __restrict__ x, const float* __restrict__ pb,
                                                const float* __restrict__ w,
                                                float* __restrict__ out, int n_nodes) {
    const int lane = threadIdx.x & 63;
    const int wv = threadIdx.x >> 6;
    const float wk = w[lane];
    const float pbv = pb[lane];
    int wid = blockIdx.x * 4 + wv;
    const int nw = gridDim.x * 4;
    for (int n = wid; n < n_nodes; n += nw) {
        float v = fmaxf(x[(size_t)n * HID + lane] + pbv, 0.f) * wk;
#pragma unroll
        for (int off = 32; off >= 1; off >>= 1) v += __shfl_xor(v, off, 64);
        if (lane == 0) out[n] = v;
    }
}

// ---------------- layer-3: segmented batch-sum -> 64-replica scratch ---------
__global__ __launch_bounds__(256) void edge_out_seg(
    const uint2* __restrict__ meta,
    const float* __restrict__ sup3, const int* __restrict__ batch,
    float* __restrict__ outR)
{
    const int lane = threadIdx.x & 63;
    const int wv = threadIdx.x >> 6;
    const int wid = blockIdx.x * 4 + wv;
    float* outw = outR + (size_t)(wid & (NREP - 1)) * NBATCH;
    const size_t base = (size_t)wid * 128;
    float acc = 0.f;
    int bcur = -1;
#pragma unroll
    for (int c = 0; c < 2; ++c) {
        const size_t i = base + c * 64 + lane;
        const uint2 m = meta[i];
        const float mv = sup3[m.x & 0xFFFFu] * __uint_as_float(m.y);
        const int b = batch[m.x >> 16];
        if (b != bcur) {
            if (bcur >= 0) atomicAdd(&outw[bcur], acc);
            bcur = b;
            acc = mv;
        } else {
            acc += mv;
        }
    }
    const int b0 = __builtin_amdgcn_readfirstlane(bcur);
    if (__all(bcur == b0)) {
#pragma unroll
        for (int off = 32; off >= 1; off >>= 1) acc += __shfl_xor(acc, off, 64);
        if (lane == 0) atomicAdd(&outw[b0], acc);
    } else {
        atomicAdd(&outw[bcur], acc);
    }
}

// ---------------- pool bias + replica reduction (block 0) --------------------
__global__ __launch_bounds__(256) void pool_bias_final(const int* __restrict__ batch,
                                                       const float* __restrict__ b_out,
                                                       const float* __restrict__ outR,
                                                       float* __restrict__ out) {
    __shared__ int cnt[NBATCH];
    if (threadIdx.x < NBATCH) cnt[threadIdx.x] = 0;
    __syncthreads();
    const int n = blockIdx.x * 256 + threadIdx.x;
    atomicAdd(&cnt[batch[n]], 1);
    __syncthreads();
    if (threadIdx.x < NBATCH && cnt[threadIdx.x])
        atomicAdd(&out[threadIdx.x], (float)cnt[threadIdx.x] * b_out[0]);
    if (blockIdx.x == 0 && threadIdx.x < NBATCH) {
        float s = 0.f;
#pragma unroll
        for (int r = 0; r < NREP; ++r) s += outR[r * NBATCH + threadIdx.x];
        atomicAdd(&out[threadIdx.x], s);
    }
}

extern "C" void kernel_launch(void* const* d_in, const int* in_sizes, int n_in,
                              void* d_out, int out_size, void* d_ws, size_t ws_size,
                              hipStream_t stream) {
    const float* nf    = (const float*)d_in[0];
    const float* ef    = (const float*)d_in[1];
    const int*   Esrc  = (const int*)d_in[2];
    const int*   Etgt  = (const int*)d_in[3];
    const int*   batch = (const int*)d_in[4];
    const float* W_in  = (const float*)d_in[5];
    const float* b_in  = (const float*)d_in[6];
    const float* W_mid = (const float*)d_in[7];
    const float* b_mid = (const float*)d_in[8];
    const float* W_out = (const float*)d_in[9];
    const float* b_out = (const float*)d_in[10];
    const float* eiW1  = (const float*)d_in[11];
    const float* eib1  = (const float*)d_in[12];
    const float* eiW2  = (const float*)d_in[13];
    const float* eib2  = (const float*)d_in[14];
    const float* emW1  = (const float*)d_in[15];
    const float* emb1  = (const float*)d_in[16];
    const float* emW2  = (const float*)d_in[17];
    const float* emb2  = (const float*)d_in[18];
    const float* eoW1  = (const float*)d_in[19];
    const float* eob1  = (const float*)d_in[20];
    const float* eoW2  = (const float*)d_in[21];
    const float* eob2  = (const float*)d_in[22];

    float* bufA   = (float*)d_ws;                        // 16MB support
    float* bufB   = bufA + (size_t)NN * HID;             // 16MB x/agg
    float* sup3   = bufB + (size_t)NN * HID;             // 256KB
    uint4* ef16   = (uint4*)(sup3 + NN);                 // 16MB sorted packed ef
    uint2* meta   = (uint2*)(ef16 + NE);                 // 8MB {src|tgt, enc3}
    uint4* ef16_t = (uint4*)(meta + NE);                 // 16MB bin-staged ef
    uint2* meta_t = (uint2*)(ef16_t + NE);               // 8MB bin-staged meta
    int* bc       = (int*)(meta_t + NE);                 // 1MB per-block bin counts
    int* cursor   = bc + NB * NBIN;                      // 1MB per-(blk,bin) cursors
    int* binStart = cursor + NB * NBIN;                  // 4KB+
    int* binTotal = binStart + NBIN + 1;                 // 4KB
    float* outR   = (float*)(binTotal + NBIN);           // 16KB replicas

    hipMemsetAsync(d_out, 0, NBATCH * sizeof(float), stream);
    // binTotal and outR are contiguous: clear both in one memset
    hipMemsetAsync(binTotal, 0, (NBIN + NREP * NBATCH) * sizeof(int), stream);

    // 2-level LDS-binned sort by Etgt (+ layer-3 enc computed in-flight)
    p1_hist<<<NB, 1024, 0, stream>>>(Etgt, bc, binTotal);
    p2_cursor<<<NBIN / 4, 256, 0, stream>>>(binTotal, bc, binStart, cursor);
    p3_scatter<<<NB, 1024, 0, stream>>>(Etgt, Esrc, ef, cursor,
                                        eoW1, eob1, eoW2, eob2, ef16_t, meta_t);
    p4_sort<<<NBIN, 256, 0, stream>>>(binStart, meta_t, ef16_t, meta, ef16);

    // layer 1
    node_linear<NODE_F, false><<<1024, 256, 0, stream>>>(nf, nullptr, W_in, bufA, NN);
    hipMemsetAsync(bufB, 0, (size_t)NN * HID * sizeof(float), stream);
    edge_layer_fused<<<2048, 256, 0, stream>>>(ef16, meta, bufA, eiW1, eib1, eiW2, eib2, bufB);
    // layer 2
    node_linear<HID, true><<<1024, 256, 0, stream>>>(bufB, b_in, W_mid, bufA, NN);
    hipMemsetAsync(bufB, 0, (size_t)NN * HID * sizeof(float), stream);
    edge_layer_fused<<<2048, 256, 0, stream>>>(ef16, meta, bufA, emW1, emb1, emW2, emb2, bufB);
    // layer 3 + pooling (exact f32, segmented batch accumulation -> replicas)
    node_dot<<<256, 256, 0, stream>>>(bufB, b_mid, W_out, sup3, NN);
    edge_out_seg<<<NE / 512, 256, 0, stream>>>(meta, sup3, batch, outR);
    pool_bias_final<<<NN / 256, 256, 0, stream>>>(batch, b_out, outR, (float*)d_out);
}